// Round 1
// baseline (757.147 us; speedup 1.0000x reference)
//
#include <hip/hip_runtime.h>
#include <hip/hip_bf16.h>
#include <stdint.h>

#define N_TOK 4096   // B*S
#define KF    8192   // IN_F
#define NF    8192   // OUT_F

typedef __attribute__((ext_vector_type(8))) short short8;
typedef __attribute__((ext_vector_type(4))) float f32x4;

#define GLOBAL_P(p) ((const __attribute__((address_space(1))) void*)(p))
#define LDS_P(p)    ((__attribute__((address_space(3))) void*)(p))

// ---------- pass 1: int8-quantize activations, store as bf16 (exact) ----------
__global__ void quant_x(const float* __restrict__ x, const float* __restrict__ scale_p,
                        uint16_t* __restrict__ a) {
    const float s = *scale_p;
    const int n8 = N_TOK * KF / 8;
    const int stride = gridDim.x * blockDim.x;
    for (int i = blockIdx.x * blockDim.x + threadIdx.x; i < n8; i += stride) {
        const float4* xp = (const float4*)(x + (size_t)i * 8);
        float4 v0 = xp[0], v1 = xp[1];
        float q[8] = {v0.x, v0.y, v0.z, v0.w, v1.x, v1.y, v1.z, v1.w};
        union { uint16_t u16[8]; short8 v; } o;
        #pragma unroll
        for (int j = 0; j < 8; ++j) {
            float t = rintf(q[j] / s);                 // round-half-even, same as jnp.round
            t = fminf(fmaxf(t, -128.f), 127.f);
            union { float f; uint32_t u; } cv; cv.f = t;
            o.u16[j] = (uint16_t)(cv.u >> 16);         // exact: ints <=128 have zero low bits
        }
        *(short8*)(a + (size_t)i * 8) = o.v;
    }
}

// ---------- pass 2: unpack nibbles + signs -> bf16 weights (exact powers of 2) ----------
__global__ void dequant_w(const int* __restrict__ packed, const int* __restrict__ signs,
                          const int* __restrict__ minexp_p, uint16_t* __restrict__ w) {
    const int me = *minexp_p;                 // -14
    const int ebase = (me + 127) << 7;        // bf16 exponent field for e=0 (normal range)
    const int n4 = NF * (KF / 2) / 4;         // packed int32 words / 4
    const int stride = gridDim.x * blockDim.x;
    for (int i = blockIdx.x * blockDim.x + threadIdx.x; i < n4; i += stride) {
        int4 p  = ((const int4*)packed)[i];
        int4 s0 = ((const int4*)signs)[(size_t)i * 2];
        int4 s1 = ((const int4*)signs)[(size_t)i * 2 + 1];
        int pw[4] = {p.x, p.y, p.z, p.w};
        int sg[8] = {s0.x, s0.y, s0.z, s0.w, s1.x, s1.y, s1.z, s1.w};
        union { uint16_t u16[8]; short8 v; } o;
        #pragma unroll
        for (int j = 0; j < 4; ++j) {
            int lo = pw[j] & 0xF, hi = (pw[j] >> 4) & 0xF;   // low nibble first
            o.u16[2 * j]     = (uint16_t)((ebase + (lo << 7)) | (sg[2 * j]     < 0 ? 0x8000 : 0));
            o.u16[2 * j + 1] = (uint16_t)((ebase + (hi << 7)) | (sg[2 * j + 1] < 0 ? 0x8000 : 0));
        }
        *(short8*)(w + (size_t)i * 8) = o.v;
    }
}

// ---------- pass 3: bf16 GEMM (m97 structure): out[M,N] = A[M,K] * W[N,K]^T * s + bias ----------
__global__ __launch_bounds__(256) void gemm_bt(
        const uint16_t* __restrict__ A, const uint16_t* __restrict__ W,
        const float* __restrict__ bias, const float* __restrict__ scale_p,
        float* __restrict__ out) {
    __shared__ uint16_t lA[128 * 32];   // 8 KB
    __shared__ uint16_t lB[128 * 32];   // 8 KB

    const int tid  = threadIdx.x;
    const int wid  = tid >> 6;
    const int lane = tid & 63;
    const int wr = wid >> 1, wc = wid & 1;       // 2x2 wave grid, 64x64 per wave
    const int bn = blockIdx.x;                   // N tile (0..63)
    const int bm = blockIdx.y;                   // M tile (0..31)
    const int rowA0 = bm * 128;
    const int colB0 = bn * 128;

    f32x4 acc[4][4] = {};

    // staging coords: issue i covers bytes [i*4096, i*4096+4096), 16B per thread
    const int o0 = tid * 16, o1 = (256 + tid) * 16;
    const int r0 = o0 >> 6, k80 = (o0 >> 4) & 3;     // row in tile, k-octet
    const int r1 = o1 >> 6, k81 = (o1 >> 4) & 3;
    const int ldsw0 = wid * 1024;                    // wave-uniform LDS dest, issue 0
    const int ldsw1 = 4096 + wid * 1024;             // issue 1

    const int rlane = lane & 15, kgrp = lane >> 4;
    const char* lAb = (const char*)lA;
    const char* lBb = (const char*)lB;

    for (int kt = 0; kt < KF / 32; ++kt) {
        const int kcol = kt * 32;
        const uint16_t* ga0 = A + (size_t)(rowA0 + r0) * KF + kcol + k80 * 8;
        const uint16_t* ga1 = A + (size_t)(rowA0 + r1) * KF + kcol + k81 * 8;
        const uint16_t* gb0 = W + (size_t)(colB0 + r0) * KF + kcol + k80 * 8;
        const uint16_t* gb1 = W + (size_t)(colB0 + r1) * KF + kcol + k81 * 8;
        __builtin_amdgcn_global_load_lds(GLOBAL_P(ga0), LDS_P((char*)lA + ldsw0), 16, 0, 0);
        __builtin_amdgcn_global_load_lds(GLOBAL_P(ga1), LDS_P((char*)lA + ldsw1), 16, 0, 0);
        __builtin_amdgcn_global_load_lds(GLOBAL_P(gb0), LDS_P((char*)lB + ldsw0), 16, 0, 0);
        __builtin_amdgcn_global_load_lds(GLOBAL_P(gb1), LDS_P((char*)lB + ldsw1), 16, 0, 0);
        __syncthreads();   // drains vmcnt(0) before barrier (compiler semantics)

        short8 af[4], bf[4];
        #pragma unroll
        for (int m = 0; m < 4; ++m)
            af[m] = *(const short8*)(lAb + ((wr * 64 + m * 16 + rlane) * 64 + kgrp * 16));
        #pragma unroll
        for (int n = 0; n < 4; ++n)
            bf[n] = *(const short8*)(lBb + ((wc * 64 + n * 16 + rlane) * 64 + kgrp * 16));

        #pragma unroll
        for (int m = 0; m < 4; ++m)
            #pragma unroll
            for (int n = 0; n < 4; ++n)
                acc[m][n] = __builtin_amdgcn_mfma_f32_16x16x32_bf16(af[m], bf[n], acc[m][n], 0, 0, 0);
        __syncthreads();
    }

    // epilogue: C/D layout col = lane&15, row = (lane>>4)*4 + r  [m89/m91 verified]
    const float s = *scale_p;
    #pragma unroll
    for (int n = 0; n < 4; ++n) {
        const int col = colB0 + wc * 64 + n * 16 + rlane;
        const float bv = bias[col];
        #pragma unroll
        for (int m = 0; m < 4; ++m) {
            const int row = rowA0 + wr * 64 + m * 16 + kgrp * 4;
            #pragma unroll
            for (int r = 0; r < 4; ++r)
                out[(size_t)(row + r) * NF + col] = acc[m][n][r] * s + bv;
        }
    }
}

extern "C" void kernel_launch(void* const* d_in, const int* in_sizes, int n_in,
                              void* d_out, int out_size, void* d_ws, size_t ws_size,
                              hipStream_t stream) {
    const float* x      = (const float*)d_in[0];
    const int*   packed = (const int*)d_in[1];
    const int*   signs  = (const int*)d_in[2];
    const float* bias   = (const float*)d_in[3];
    const float* scale  = (const float*)d_in[4];
    const int*   minexp = (const int*)d_in[5];
    float* out = (float*)d_out;

    uint16_t* A = (uint16_t*)d_ws;                                       // 64 MiB
    uint16_t* W = (uint16_t*)((char*)d_ws + (size_t)N_TOK * KF * 2);     // 128 MiB

    quant_x<<<2048, 256, 0, stream>>>(x, scale, A);
    dequant_w<<<2048, 256, 0, stream>>>(packed, signs, minexp, W);
    dim3 grid(NF / 128, N_TOK / 128);
    gemm_bt<<<grid, 256, 0, stream>>>(A, W, bias, scale, out);
}